// Round 24
// baseline (246.808 us; speedup 1.0000x reference)
//
#include <hip/hip_runtime.h>
#include <stdint.h>

// MultiHeadAttention: B=4, S=2048, D_MODEL=1024, H=16, dh=64
// R24: launch-count reduction. attn/gemm bodies = R22 (proven; attn pinned
//      at ~117us across 5 variants -> sum-of-kernels ~207 vs 234 total =
//      ~27us of serial launch gaps). If ws_size >= ~126MB: 3 separate X
//      buffers -> ONE convert launch + ONE z=3 QKV gemm launch (10 -> 6
//      launches). Runtime branch on ws_size (deterministic, graph-safe);
//      else exact R22 path.

typedef unsigned short u16;
typedef __attribute__((ext_vector_type(8))) short bf16x8;
typedef __attribute__((ext_vector_type(4))) short bf16x4;
typedef __attribute__((ext_vector_type(4))) float f32x4;

#define LOG2E 1.4426950408889634f

__device__ __forceinline__ u16 f2bf(float f) {
  uint32_t u = __builtin_bit_cast(uint32_t, f);
  u += 0x7fffu + ((u >> 16) & 1u);   // RNE
  return (u16)(u >> 16);
}
__device__ __forceinline__ uint32_t cvt_pk(float a, float b) {
  uint32_t r;
  asm("v_cvt_pk_bf16_f32 %0, %1, %2" : "=v"(r) : "v"(a), "v"(b));
  return r;
}
__device__ __forceinline__ void gload16(const u16* g, u16* l) {
  __builtin_amdgcn_global_load_lds(
      (const __attribute__((address_space(1))) uint32_t*)(const void*)g,
      (__attribute__((address_space(3))) uint32_t*)(void*)l, 16, 0, 0);
}
__device__ __forceinline__ f32x4 mfma16(bf16x4 a, bf16x4 b, f32x4 c) {
#if __has_builtin(__builtin_amdgcn_mfma_f32_16x16x16bf16_1k)
  return __builtin_amdgcn_mfma_f32_16x16x16bf16_1k(a, b, c, 0, 0, 0);
#else
  f32x4 d = c;
  asm volatile("v_mfma_f32_16x16x16_bf16 %0, %1, %2, %0"
               : "+v"(d) : "v"(a), "v"(b));
  return d;
#endif
}

// ---------------- fp32 -> bf16 convert (single input) -----------------
__global__ __launch_bounds__(256) void convert_x(
    const float* __restrict__ X, u16* __restrict__ Xb)
{
  const size_t i = ((size_t)blockIdx.x * 256 + threadIdx.x) * 8;
  const float4 a = *(const float4*)(X + i);
  const float4 b = *(const float4*)(X + i + 4);
  uint4 o;
  o.x = cvt_pk(a.x, a.y); o.y = cvt_pk(a.z, a.w);
  o.z = cvt_pk(b.x, b.y); o.w = cvt_pk(b.z, b.w);
  *(uint4*)(Xb + i) = o;
}

// ---------------- fp32 -> bf16 convert, all three inputs --------------
__global__ __launch_bounds__(256) void convert_all(
    const float* __restrict__ Xq, const float* __restrict__ Xk,
    const float* __restrict__ Xv, u16* __restrict__ Out /* 3x8M u16 */)
{
  const int z = blockIdx.x >> 12;           // 4096 blocks per input
  const int inner = blockIdx.x & 4095;
  const float* X = (z == 0) ? Xq : (z == 1) ? Xk : Xv;
  const size_t i = ((size_t)inner * 256 + threadIdx.x) * 8;
  const float4 a = *(const float4*)(X + i);
  const float4 b = *(const float4*)(X + i + 4);
  uint4 o;
  o.x = cvt_pk(a.x, a.y); o.y = cvt_pk(a.z, a.w);
  o.z = cvt_pk(b.x, b.y); o.w = cvt_pk(b.z, b.w);
  *(uint4*)(Out + ((size_t)z << 23) + i) = o;
}

// ---------------- mask premultiply: M2 = f32(mask * -1e9*log2e) -------
__global__ __launch_bounds__(256) void prep_mask(
    const float* __restrict__ mask, float* __restrict__ M2)
{
  const int i = blockIdx.x * 256 + threadIdx.x;
  M2[i] = mask[i] * (-1.0e9f * LOG2E);
}

// ---------------- weight transpose + bf16 convert ----------------
__global__ __launch_bounds__(256) void transpose_w(
    const float* __restrict__ W0, const float* __restrict__ W1,
    const float* __restrict__ W2, const float* __restrict__ W3,
    u16* __restrict__ Wt)
{
  const int z = blockIdx.z;
  const float* W = (z == 0) ? W0 : (z == 1) ? W1 : (z == 2) ? W2 : W3;
  u16* T = Wt + ((size_t)z << 20);
  const int n0 = blockIdx.x * 64, k0 = blockIdx.y * 64;
  const int tid = threadIdx.x;
  const int r = tid >> 4, c4 = (tid & 15) * 4;
  __shared__ float t[64][65];
#pragma unroll
  for (int j = 0; j < 4; ++j) {
    const int row = r + j * 16;
    const float4 v = *(const float4*)(W + (size_t)(k0 + row) * 1024 + n0 + c4);
    t[c4 + 0][row] = v.x; t[c4 + 1][row] = v.y;
    t[c4 + 2][row] = v.z; t[c4 + 3][row] = v.w;
  }
  __syncthreads();
#pragma unroll
  for (int j = 0; j < 4; ++j) {
    const int nrow = r + j * 16;
    uint2 o;
    o.x = cvt_pk(t[nrow][c4 + 0], t[nrow][c4 + 1]);
    o.y = cvt_pk(t[nrow][c4 + 2], t[nrow][c4 + 3]);
    *(uint2*)(T + (size_t)(n0 + nrow) * 1024 + k0 + c4) = o;
  }
}

// ================= shared GEMM body (BK=64, counted-vmcnt dbuf) =======
// 128x128 tile, 512 thr, wave grid 2x4 (64x32/wave), LDS [128][64] u16,
// slot swizzle ^(row&7) (rule #21). epilogue mode: 0=Q 1=K 2=V^T 3=f32.
__device__ __forceinline__ void gemm_body(
    const u16* __restrict__ A, const u16* __restrict__ Wt,
    const float* __restrict__ Bi, u16* __restrict__ O16,
    float* __restrict__ O32, int mode, int m0, int n0,
    u16 (*As)[8192], u16 (*Bs)[8192])
{
  const int tid = threadIdx.x;
  const int w = tid >> 6, l = tid & 63, lo = l & 15, hi = l >> 4;
  const int wr = w >> 2, wc = w & 3;

  const f32x4 fz = {0.f, 0.f, 0.f, 0.f};
  f32x4 acc[4][2];
#pragma unroll
  for (int m = 0; m < 4; ++m)
#pragma unroll
    for (int n = 0; n < 2; ++n) acc[m][n] = fz;

  const int srow = tid >> 3;
  const int ssl  = (tid & 7) ^ (srow & 7);
  const u16* ga = A  + (size_t)(m0 + srow) * 1024 + ssl * 8;
  const u16* gb = Wt + (size_t)(n0 + srow) * 1024 + ssl * 8;

#define GST(k0_, b_)                                          \
  do {                                                        \
    gload16(ga + (k0_),             &As[b_][w * 512]);        \
    gload16(ga + (k0_) + 64 * 1024, &As[b_][4096 + w * 512]); \
    gload16(gb + (k0_),             &Bs[b_][w * 512]);        \
    gload16(gb + (k0_) + 64 * 1024, &Bs[b_][4096 + w * 512]); \
  } while (0)

  GST(0, 0);
  __syncthreads();

  for (int kt = 0; kt < 16; ++kt) {
    const int cur = kt & 1;
    GST(((kt + 1) & 15) * 64, cur ^ 1);
    asm volatile("s_waitcnt vmcnt(4)" ::: "memory");
    __builtin_amdgcn_s_barrier();

#pragma unroll
    for (int k32 = 0; k32 < 2; ++k32) {
      bf16x8 af[4], bf[2];
#pragma unroll
      for (int m = 0; m < 4; ++m) {
        const int row = wr * 64 + m * 16 + lo;
        const int sl = (k32 * 4 + hi) ^ (row & 7);
        af[m] = *(const bf16x8*)&As[cur][row * 64 + sl * 8];
      }
#pragma unroll
      for (int n = 0; n < 2; ++n) {
        const int row = wc * 32 + n * 16 + lo;
        const int sl = (k32 * 4 + hi) ^ (row & 7);
        bf[n] = *(const bf16x8*)&Bs[cur][row * 64 + sl * 8];
      }
#pragma unroll
      for (int m = 0; m < 4; ++m)
#pragma unroll
        for (int n = 0; n < 2; ++n)
          acc[m][n] = __builtin_amdgcn_mfma_f32_16x16x32_bf16(af[m], bf[n], acc[m][n], 0, 0, 0);
    }

    asm volatile("s_waitcnt lgkmcnt(0)" ::: "memory");
    __builtin_amdgcn_s_barrier();
  }
#undef GST

#pragma unroll
  for (int m = 0; m < 4; ++m) {
#pragma unroll
    for (int n = 0; n < 2; ++n) {
      const int col = n0 + wc * 32 + n * 16 + lo;
      const float bc = Bi[col];
      const int h = col >> 6, d = col & 63;
#pragma unroll
      for (int i = 0; i < 4; ++i) {
        const int r = m0 + wr * 64 + m * 16 + hi * 4 + i;
        const int b = r >> 11, s = r & 2047;
        float v = acc[m][n][i] + bc;
        if (mode == 0) {
          v *= 0.125f * LOG2E;
          O16[((size_t)((b * 16 + h) * 2048 + s)) * 64 + d] = f2bf(v);
        } else if (mode == 1) {
          O16[((size_t)((b * 16 + h) * 2048 + s)) * 64 + d] = f2bf(v);
        } else if (mode == 2) {
          O16[((size_t)((b * 16 + h) * 64 + d)) * 2048 + s] = f2bf(v);
        } else {
          O32[(size_t)r * 1024 + col] = v;
        }
      }
    }
  }
}

// single-operand gemm (slow path + output projection)
__global__ __launch_bounds__(512, 4) void gemm_proj(
    const u16* __restrict__ A, const u16* __restrict__ Wt,
    const float* __restrict__ Bi, u16* __restrict__ O16,
    float* __restrict__ O32, int mode)
{
  const int bid = blockIdx.x;
  const int nid = (bid & 7) * 64 + (bid >> 3);
  const int n0 = (nid & 7) * 128;
  const int m0 = (nid >> 3) * 128;
  __shared__ __align__(16) u16 As[2][8192];
  __shared__ __align__(16) u16 Bs[2][8192];
  gemm_body(A, Wt, Bi, O16, O32, mode, m0, n0, As, Bs);
}

// fused z=3 QKV projection (fast path): grid 1536, XCD-chunked
__global__ __launch_bounds__(512, 4) void gemm_qkv3(
    const u16* __restrict__ X3, const u16* __restrict__ Wt3,
    const float* __restrict__ Bq, const float* __restrict__ Bk,
    const float* __restrict__ Bv, u16* __restrict__ Qo,
    u16* __restrict__ Ko, u16* __restrict__ Vto)
{
  const int bid = blockIdx.x;
  const int nid = (bid & 7) * 192 + (bid >> 3);
  const int z = nid >> 9;
  const int rem = nid & 511;
  const int n0 = (rem & 7) * 128;
  const int m0 = (rem >> 3) * 128;
  const u16* A  = X3 + ((size_t)z << 23);
  const u16* Wt = Wt3 + ((size_t)z << 20);
  const float* Bi = (z == 0) ? Bq : (z == 1) ? Bk : Bv;
  u16* O16 = (z == 0) ? Qo : (z == 1) ? Ko : Vto;
  __shared__ __align__(16) u16 As[2][8192];
  __shared__ __align__(16) u16 Bs[2][8192];
  gemm_body(A, Wt, Bi, O16, nullptr, z, m0, n0, As, Bs);
}

// ---------------- flash attention (8 waves x 32 q/wave, R20/R22) ------
__global__ __launch_bounds__(512, 4) void attn(
    const u16* __restrict__ Q, const u16* __restrict__ K,
    const u16* __restrict__ Vt, const float* __restrict__ M2,
    u16* __restrict__ Ctx)
{
  const int bid = blockIdx.x;
  const int nid = (bid & 7) * 64 + (bid >> 3);
  const int qt = nid & 7;
  const int bh = nid >> 3;
  const int b = bh >> 4, h = bh & 15;
  const int tid = threadIdx.x;
  const int w = tid >> 6, l = tid & 63, lo = l & 15, hi = l >> 4;

  __shared__ __align__(16) u16 Kl[2][4096];
  __shared__ __align__(16) u16 Vl[2][4096];
  __shared__ __align__(16) float Msk[2048];

  const u16* Qb = Q + (size_t)bh * (2048 * 64);
  const u16* Kb = K + (size_t)bh * (2048 * 64);
  const u16* Vb = Vt + (size_t)bh * (64 * 2048);

  *(float4*)&Msk[tid * 4] = *(const float4*)(M2 + (size_t)b * 2048 + tid * 4);

  const int qrow0 = qt * 256 + w * 32 + lo;
  const bf16x8 qa00 = *(const bf16x8*)(Qb + (size_t)qrow0 * 64 + hi * 8);
  const bf16x8 qa01 = *(const bf16x8*)(Qb + (size_t)qrow0 * 64 + 32 + hi * 8);
  const bf16x8 qa10 = *(const bf16x8*)(Qb + (size_t)(qrow0 + 16) * 64 + hi * 8);
  const bf16x8 qa11 = *(const bf16x8*)(Qb + (size_t)(qrow0 + 16) * 64 + 32 + hi * 8);

  const f32x4 fz = {0.f, 0.f, 0.f, 0.f};
  f32x4 o0[4] = {fz, fz, fz, fz};
  f32x4 o1[4] = {fz, fz, fz, fz};
  f32x4 ol0 = fz, ol1 = fz;
  const short oneb = (short)0x3F80;
  const bf16x4 ones = {oneb, oneb, oneb, oneb};
  const int lo7 = lo & 7;

  const int rowA = tid >> 3;
  const int slA  = (tid & 7) ^ (rowA & 7);
  const u16* gK = Kb + (size_t)rowA * 64 + slA * 8;
  const u16* gV = Vb + (size_t)rowA * 2048 + slA * 8;

#define STAGE(kt_, buf_)                                    \
  do {                                                      \
    gload16(gK + (size_t)(kt_) * 4096, &Kl[buf_][w * 512]); \
    gload16(gV + (kt_) * 64,           &Vl[buf_][w * 512]); \
  } while (0)

  STAGE(0, 0);
  __syncthreads();

  for (int kt = 0; kt < 32; ++kt) {
    const int cur = kt & 1;
    STAGE((kt + 1) & 31, cur ^ 1);
    asm volatile("s_waitcnt vmcnt(2)" ::: "memory");
    __builtin_amdgcn_s_barrier();

    const int kv0 = kt * 64;
    const u16* Kc = &Kl[cur][0];
    const u16* Vc = &Vl[cur][0];

    f32x4 st0[4], st1[4];
    __builtin_amdgcn_s_setprio(1);
#pragma unroll
    for (int f = 0; f < 4; ++f) {
      const int krow = (f * 16 + lo) * 64;
      const bf16x8 kb0 = *(const bf16x8*)&Kc[krow + ((hi ^ lo7) << 3)];
      const bf16x8 kb1 = *(const bf16x8*)&Kc[krow + (((4 + hi) ^ lo7) << 3)];
      const f32x4 c = *(const f32x4*)&Msk[kv0 + 16 * f + 4 * hi];
      f32x4 a0 = __builtin_amdgcn_mfma_f32_16x16x32_bf16(kb0, qa00, c, 0, 0, 0);
      st0[f] = __builtin_amdgcn_mfma_f32_16x16x32_bf16(kb1, qa01, a0, 0, 0, 0);
      f32x4 a1 = __builtin_amdgcn_mfma_f32_16x16x32_bf16(kb0, qa10, c, 0, 0, 0);
      st1[f] = __builtin_amdgcn_mfma_f32_16x16x32_bf16(kb1, qa11, a1, 0, 0, 0);
    }
    __builtin_amdgcn_s_setprio(0);

    union { uint32_t u[2]; bf16x4 v; } pa0[4], pa1[4];
#pragma unroll
    for (int f = 0; f < 2; ++f) {
      pa0[f].u[0] = cvt_pk(exp2f(st0[f][0]), exp2f(st0[f][1]));
      pa0[f].u[1] = cvt_pk(exp2f(st0[f][2]), exp2f(st0[f][3]));
      pa1[f].u[0] = cvt_pk(exp2f(st1[f][0]), exp2f(st1[f][1]));
      pa1[f].u[1] = cvt_pk(exp2f(st1[f][2]), exp2f(st1[f][3]));
    }

    __builtin_amdgcn_s_setprio(1);
#pragma unroll
    for (int f = 0; f < 2; ++f) {
      ol0 = mfma16(pa0[f].v, ones, ol0);
      ol1 = mfma16(pa1[f].v, ones, ol1);
#pragma unroll
      for (int nf = 0; nf < 4; ++nf) {
        const int vrow = (lo + 16 * nf) * 64;
        const int slot = (((2 * f + (hi >> 1)) ^ lo7) << 3) + ((hi & 1) << 2);
        const bf16x4 vb = *(const bf16x4*)&Vc[vrow + slot];
        o0[nf] = mfma16(pa0[f].v, vb, o0[nf]);
        o1[nf] = mfma16(pa1[f].v, vb, o1[nf]);
      }
    }
#pragma unroll
    for (int f = 2; f < 4; ++f) {
      pa0[f].u[0] = cvt_pk(exp2f(st0[f][0]), exp2f(st0[f][1]));
      pa0[f].u[1] = cvt_pk(exp2f(st0[f][2]), exp2f(st0[f][3]));
      pa1[f].u[0] = cvt_pk(exp2f(st1[f][0]), exp2f(st1[f][1]));
      pa1[f].u[1] = cvt_pk(exp2f(st1[f][2]), exp2f(st1[f][3]));
    }
#pragma unroll
    for (int f = 2; f < 4; ++f) {
      ol0 = mfma16(pa0[f].v, ones, ol0);
      ol1 = mfma16(pa1[f].v, ones, ol1);
#pragma unroll
      for (int nf = 0; nf < 4; ++nf) {
        const int vrow = (lo + 16 * nf) * 64;
        const int slot = (((2 * f + (hi >> 1)) ^ lo7) << 3) + ((hi & 1) << 2);
        const bf16x4 vb = *(const bf16x4*)&Vc[vrow + slot];
        o0[nf] = mfma16(pa0[f].v, vb, o0[nf]);
        o1[nf] = mfma16(pa1[f].v, vb, o1[nf]);
      }
    }
    __builtin_amdgcn_s_setprio(0);

    asm volatile("s_waitcnt lgkmcnt(0)" ::: "memory");
    __builtin_amdgcn_s_barrier();
  }
#undef STAGE

  float inv0[4], inv1[4];
#pragma unroll
  for (int i = 0; i < 4; ++i) { inv0[i] = 1.f / ol0[i]; inv1[i] = 1.f / ol1[i]; }
#pragma unroll
  for (int nf = 0; nf < 4; ++nf) {
#pragma unroll
    for (int i = 0; i < 4; ++i) {
      const int s0 = qt * 256 + w * 32 + hi * 4 + i;
      const int d = nf * 16 + lo;
      Ctx[((size_t)((b * 2048 + s0) * 16 + h)) * 64 + d] = f2bf(o0[nf][i] * inv0[i]);
      Ctx[((size_t)((b * 2048 + s0 + 16) * 16 + h)) * 64 + d] = f2bf(o1[nf][i] * inv1[i]);
    }
  }
}

extern "C" void kernel_launch(void* const* d_in, const int* in_sizes, int n_in,
                              void* d_out, int out_size, void* d_ws, size_t ws_size,
                              hipStream_t stream) {
  const float* q_in = (const float*)d_in[0];
  const float* k_in = (const float*)d_in[1];
  const float* v_in = (const float*)d_in[2];
  const float* mask = (const float*)d_in[3];
  const float* wq = (const float*)d_in[4];
  const float* bq = (const float*)d_in[5];
  const float* wk = (const float*)d_in[6];
  const float* bk = (const float*)d_in[7];
  const float* wv = (const float*)d_in[8];
  const float* bv = (const float*)d_in[9];
  const float* wo = (const float*)d_in[10];
  const float* bo = (const float*)d_in[11];

  u16* ws  = (u16*)d_ws;
  const size_t M8 = (size_t)8192 * 1024;          // 8M u16 = 16MB

  if (ws_size >= 127ull * 1024 * 1024) {
    // FAST PATH (6 launches): wT 8MB | X3 48MB | Q,K,Vt 48MB | ctx 16MB | M2
    u16* wt3 = ws;                                 // wtq/wtk/wtv
    u16* wto = wt3 + 3u * (1u << 20);
    u16* X3  = wto + (1u << 20);
    u16* Qb  = X3 + 3 * M8;
    u16* Kb  = Qb + M8;
    u16* Vtb = Kb + M8;
    u16* ctx = Vtb + M8;
    float* M2 = (float*)(ctx + M8);

    transpose_w<<<dim3(16, 16, 4), 256, 0, stream>>>(wq, wk, wv, wo, wt3);
    prep_mask<<<32, 256, 0, stream>>>(mask, M2);
    convert_all<<<12288, 256, 0, stream>>>(q_in, k_in, v_in, X3);
    gemm_qkv3<<<1536, 512, 0, stream>>>(X3, wt3, bq, bk, bv, Qb, Kb, Vtb);
    attn<<<512, 512, 0, stream>>>(Qb, Kb, Vtb, M2, ctx);
    gemm_proj<<<512, 512, 0, stream>>>(ctx, wto, bo, nullptr, (float*)d_out, 3);
  } else {
    // SLOW PATH: exact R22 (72MB + M2)
    u16* wtq = ws;
    u16* wtk = wtq + (1u << 20);
    u16* wtv = wtk + (1u << 20);
    u16* wto = wtv + (1u << 20);
    u16* Qb  = wto + (1u << 20);
    u16* Kb  = Qb + M8;
    u16* Vtb = Kb + M8;
    u16* xbf = Vtb + M8;
    u16* ctx = xbf;
    float* M2 = (float*)(xbf + M8);

    transpose_w<<<dim3(16, 16, 4), 256, 0, stream>>>(wq, wk, wv, wo, wtq);
    prep_mask<<<32, 256, 0, stream>>>(mask, M2);
    convert_x<<<4096, 256, 0, stream>>>(q_in, xbf);
    gemm_proj<<<512, 512, 0, stream>>>(xbf, wtq, bq, Qb, nullptr, 0);
    convert_x<<<4096, 256, 0, stream>>>(k_in, xbf);
    gemm_proj<<<512, 512, 0, stream>>>(xbf, wtk, bk, Kb, nullptr, 1);
    convert_x<<<4096, 256, 0, stream>>>(v_in, xbf);
    gemm_proj<<<512, 512, 0, stream>>>(xbf, wtv, bv, Vtb, nullptr, 2);
    attn<<<512, 512, 0, stream>>>(Qb, Kb, Vtb, M2, ctx);
    gemm_proj<<<512, 512, 0, stream>>>(ctx, wto, bo, nullptr, (float*)d_out, 3);
  }
}

// Round 25
// 233.974 us; speedup vs baseline: 1.0548x; 1.0548x over previous
//
#include <hip/hip_runtime.h>
#include <stdint.h>

// MultiHeadAttention: B=4, S=2048, D_MODEL=1024, H=16, dh=64
// R25 = R22 verbatim (best measured: 234.3us). R24's launch fusion regressed
// (harness graph-replays, so launch overhead was already amortized; fusion
// lost X-panel L2 warmth). attn pinned ~117us across 6 variants (pipe-
// balanced floor); gemms ~13.5us (128^2-tile practical ceiling); converts
// HBM-bound. This restores the plateau configuration.

typedef unsigned short u16;
typedef __attribute__((ext_vector_type(8))) short bf16x8;
typedef __attribute__((ext_vector_type(4))) short bf16x4;
typedef __attribute__((ext_vector_type(4))) float f32x4;

#define LOG2E 1.4426950408889634f

__device__ __forceinline__ u16 f2bf(float f) {
  uint32_t u = __builtin_bit_cast(uint32_t, f);
  u += 0x7fffu + ((u >> 16) & 1u);   // RNE
  return (u16)(u >> 16);
}
// packed f32x2 -> bf16x2 (RNE), single VALU op; no builtin on gfx950 (m240)
__device__ __forceinline__ uint32_t cvt_pk(float a, float b) {
  uint32_t r;
  asm("v_cvt_pk_bf16_f32 %0, %1, %2" : "=v"(r) : "v"(a), "v"(b));
  return r;
}
// async global->LDS, 16B per lane; LDS dest = wave-uniform base + lane*16
__device__ __forceinline__ void gload16(const u16* g, u16* l) {
  __builtin_amdgcn_global_load_lds(
      (const __attribute__((address_space(1))) uint32_t*)(const void*)g,
      (__attribute__((address_space(3))) uint32_t*)(void*)l, 16, 0, 0);
}
// 16x16x16 bf16 MFMA (K=16)
__device__ __forceinline__ f32x4 mfma16(bf16x4 a, bf16x4 b, f32x4 c) {
#if __has_builtin(__builtin_amdgcn_mfma_f32_16x16x16bf16_1k)
  return __builtin_amdgcn_mfma_f32_16x16x16bf16_1k(a, b, c, 0, 0, 0);
#else
  f32x4 d = c;
  asm volatile("v_mfma_f32_16x16x16_bf16 %0, %1, %2, %0"
               : "+v"(d) : "v"(a), "v"(b));
  return d;
#endif
}

// ---------------- fp32 -> bf16 convert (per-z X panel) ----------------
__global__ __launch_bounds__(256) void convert_x(
    const float* __restrict__ X, u16* __restrict__ Xb)
{
  const size_t i = ((size_t)blockIdx.x * 256 + threadIdx.x) * 8;
  const float4 a = *(const float4*)(X + i);
  const float4 b = *(const float4*)(X + i + 4);
  uint4 o;
  o.x = cvt_pk(a.x, a.y); o.y = cvt_pk(a.z, a.w);
  o.z = cvt_pk(b.x, b.y); o.w = cvt_pk(b.z, b.w);
  *(uint4*)(Xb + i) = o;
}

// ---------------- mask premultiply: M2 = f32(mask * -1e9*log2e) -------
__global__ __launch_bounds__(256) void prep_mask(
    const float* __restrict__ mask, float* __restrict__ M2)
{
  const int i = blockIdx.x * 256 + threadIdx.x;
  M2[i] = mask[i] * (-1.0e9f * LOG2E);
}

// ---------------- weight transpose + bf16 convert ----------------
__global__ __launch_bounds__(256) void transpose_w(
    const float* __restrict__ W0, const float* __restrict__ W1,
    const float* __restrict__ W2, const float* __restrict__ W3,
    u16* __restrict__ Wt)
{
  const int z = blockIdx.z;
  const float* W = (z == 0) ? W0 : (z == 1) ? W1 : (z == 2) ? W2 : W3;
  u16* T = Wt + ((size_t)z << 20);
  const int n0 = blockIdx.x * 64, k0 = blockIdx.y * 64;
  const int tid = threadIdx.x;
  const int r = tid >> 4, c4 = (tid & 15) * 4;
  __shared__ float t[64][65];
#pragma unroll
  for (int j = 0; j < 4; ++j) {
    const int row = r + j * 16;
    const float4 v = *(const float4*)(W + (size_t)(k0 + row) * 1024 + n0 + c4);
    t[c4 + 0][row] = v.x; t[c4 + 1][row] = v.y;
    t[c4 + 2][row] = v.z; t[c4 + 3][row] = v.w;
  }
  __syncthreads();
#pragma unroll
  for (int j = 0; j < 4; ++j) {
    const int nrow = r + j * 16;
    uint2 o;
    o.x = cvt_pk(t[nrow][c4 + 0], t[nrow][c4 + 1]);
    o.y = cvt_pk(t[nrow][c4 + 2], t[nrow][c4 + 3]);
    *(uint2*)(T + (size_t)(n0 + nrow) * 1024 + k0 + c4) = o;
  }
}

// ---------------- projection GEMM (BK=64, counted-vmcnt dbuf) ---------
// 512 blocks x 512 thr, 128x128 tile, wave grid 2x4 (64x32/wave), BK=64.
// LDS [128][64] u16; swizzle slot^(row&7) on pre-swizzled gload source +
// frag reads (rule #21). 16 MFMA / K-iter.
// mode: 0=Q (scale, BHSd), 1=K (BHSd), 2=V^T (BHdS), 3=out fp32.
__global__ __launch_bounds__(512, 4) void gemm_proj(
    const u16* __restrict__ A, const u16* __restrict__ Wt,
    const float* __restrict__ Bi, u16* __restrict__ O16,
    float* __restrict__ O32, int mode)
{
  const int bid = blockIdx.x;
  const int nid = (bid & 7) * 64 + (bid >> 3);   // XCD-chunked (512 blocks)
  const int n0 = (nid & 7) * 128;
  const int m0 = (nid >> 3) * 128;
  const int tid = threadIdx.x;
  const int w = tid >> 6, l = tid & 63, lo = l & 15, hi = l >> 4;
  const int wr = w >> 2, wc = w & 3;             // 2x4 wave grid

  __shared__ __align__(16) u16 As[2][8192];      // [128][64]
  __shared__ __align__(16) u16 Bs[2][8192];

  const f32x4 fz = {0.f, 0.f, 0.f, 0.f};
  f32x4 acc[4][2];
#pragma unroll
  for (int m = 0; m < 4; ++m)
#pragma unroll
    for (int n = 0; n < 2; ++n) acc[m][n] = fz;

  const int srow = tid >> 3;
  const int ssl  = (tid & 7) ^ (srow & 7);
  const u16* ga = A  + (size_t)(m0 + srow) * 1024 + ssl * 8;
  const u16* gb = Wt + (size_t)(n0 + srow) * 1024 + ssl * 8;

#define GST(k0_, b_)                                          \
  do {                                                        \
    gload16(ga + (k0_),             &As[b_][w * 512]);        \
    gload16(ga + (k0_) + 64 * 1024, &As[b_][4096 + w * 512]); \
    gload16(gb + (k0_),             &Bs[b_][w * 512]);        \
    gload16(gb + (k0_) + 64 * 1024, &Bs[b_][4096 + w * 512]); \
  } while (0)

  GST(0, 0);
  __syncthreads();   // prologue: tile 0 visible (full drain once)

  for (int kt = 0; kt < 16; ++kt) {
    const int cur = kt & 1;
    GST(((kt + 1) & 15) * 64, cur ^ 1);  // prefetch next K-tile (kt=15 benign)
    asm volatile("s_waitcnt vmcnt(4)" ::: "memory");  // tile kt's 4 landed
    __builtin_amdgcn_s_barrier();                      // ...for all waves

#pragma unroll
    for (int k32 = 0; k32 < 2; ++k32) {
      bf16x8 af[4], bf[2];
#pragma unroll
      for (int m = 0; m < 4; ++m) {
        const int row = wr * 64 + m * 16 + lo;
        const int sl = (k32 * 4 + hi) ^ (row & 7);
        af[m] = *(const bf16x8*)&As[cur][row * 64 + sl * 8];
      }
#pragma unroll
      for (int n = 0; n < 2; ++n) {
        const int row = wc * 32 + n * 16 + lo;
        const int sl = (k32 * 4 + hi) ^ (row & 7);
        bf[n] = *(const bf16x8*)&Bs[cur][row * 64 + sl * 8];
      }
#pragma unroll
      for (int m = 0; m < 4; ++m)
#pragma unroll
        for (int n = 0; n < 2; ++n)
          acc[m][n] = __builtin_amdgcn_mfma_f32_16x16x32_bf16(af[m], bf[n], acc[m][n], 0, 0, 0);
    }

    asm volatile("s_waitcnt lgkmcnt(0)" ::: "memory");  // frag reads retired
    __builtin_amdgcn_s_barrier();                        // safe to overwrite
  }
#undef GST

#pragma unroll
  for (int m = 0; m < 4; ++m) {
#pragma unroll
    for (int n = 0; n < 2; ++n) {
      const int col = n0 + wc * 32 + n * 16 + lo;   // col = h*64 + d
      const float bc = Bi[col];
      const int h = col >> 6, d = col & 63;
#pragma unroll
      for (int i = 0; i < 4; ++i) {
        const int r = m0 + wr * 64 + m * 16 + hi * 4 + i;  // r = b*2048 + s
        const int b = r >> 11, s = r & 2047;
        float v = acc[m][n][i] + bc;
        if (mode == 0) {
          v *= 0.125f * LOG2E;  // fold 1/sqrt(dh) and log2(e)
          O16[((size_t)((b * 16 + h) * 2048 + s)) * 64 + d] = f2bf(v);
        } else if (mode == 1) {
          O16[((size_t)((b * 16 + h) * 2048 + s)) * 64 + d] = f2bf(v);
        } else if (mode == 2) {
          O16[((size_t)((b * 16 + h) * 64 + d)) * 2048 + s] = f2bf(v);
        } else {
          O32[(size_t)r * 1024 + col] = v;
        }
      }
    }
  }
}

// ---------------- flash attention (8 waves x 32 q/wave, R20 exact) ----
__global__ __launch_bounds__(512, 4) void attn(
    const u16* __restrict__ Q, const u16* __restrict__ K,
    const u16* __restrict__ Vt, const float* __restrict__ M2,
    u16* __restrict__ Ctx)
{
  const int bid = blockIdx.x;
  const int nid = (bid & 7) * 64 + (bid >> 3);
  const int qt = nid & 7;
  const int bh = nid >> 3;
  const int b = bh >> 4, h = bh & 15;
  const int tid = threadIdx.x;
  const int w = tid >> 6, l = tid & 63, lo = l & 15, hi = l >> 4;

  __shared__ __align__(16) u16 Kl[2][4096];
  __shared__ __align__(16) u16 Vl[2][4096];
  __shared__ __align__(16) float Msk[2048];

  const u16* Qb = Q + (size_t)bh * (2048 * 64);
  const u16* Kb = K + (size_t)bh * (2048 * 64);
  const u16* Vb = Vt + (size_t)bh * (64 * 2048);

  *(float4*)&Msk[tid * 4] = *(const float4*)(M2 + (size_t)b * 2048 + tid * 4);

  const int qrow0 = qt * 256 + w * 32 + lo;
  const bf16x8 qa00 = *(const bf16x8*)(Qb + (size_t)qrow0 * 64 + hi * 8);
  const bf16x8 qa01 = *(const bf16x8*)(Qb + (size_t)qrow0 * 64 + 32 + hi * 8);
  const bf16x8 qa10 = *(const bf16x8*)(Qb + (size_t)(qrow0 + 16) * 64 + hi * 8);
  const bf16x8 qa11 = *(const bf16x8*)(Qb + (size_t)(qrow0 + 16) * 64 + 32 + hi * 8);

  const f32x4 fz = {0.f, 0.f, 0.f, 0.f};
  f32x4 o0[4] = {fz, fz, fz, fz};
  f32x4 o1[4] = {fz, fz, fz, fz};
  f32x4 ol0 = fz, ol1 = fz;
  const short oneb = (short)0x3F80;
  const bf16x4 ones = {oneb, oneb, oneb, oneb};
  const int lo7 = lo & 7;

  const int rowA = tid >> 3;
  const int slA  = (tid & 7) ^ (rowA & 7);
  const u16* gK = Kb + (size_t)rowA * 64 + slA * 8;
  const u16* gV = Vb + (size_t)rowA * 2048 + slA * 8;

#define STAGE(kt_, buf_)                                    \
  do {                                                      \
    gload16(gK + (size_t)(kt_) * 4096, &Kl[buf_][w * 512]); \
    gload16(gV + (kt_) * 64,           &Vl[buf_][w * 512]); \
  } while (0)

  STAGE(0, 0);
  __syncthreads();

  for (int kt = 0; kt < 32; ++kt) {
    const int cur = kt & 1;
    STAGE((kt + 1) & 31, cur ^ 1);
    asm volatile("s_waitcnt vmcnt(2)" ::: "memory");
    __builtin_amdgcn_s_barrier();

    const int kv0 = kt * 64;
    const u16* Kc = &Kl[cur][0];
    const u16* Vc = &Vl[cur][0];

    f32x4 st0[4], st1[4];
    __builtin_amdgcn_s_setprio(1);
#pragma unroll
    for (int f = 0; f < 4; ++f) {
      const int krow = (f * 16 + lo) * 64;
      const bf16x8 kb0 = *(const bf16x8*)&Kc[krow + ((hi ^ lo7) << 3)];
      const bf16x8 kb1 = *(const bf16x8*)&Kc[krow + (((4 + hi) ^ lo7) << 3)];
      const f32x4 c = *(const f32x4*)&Msk[kv0 + 16 * f + 4 * hi];
      f32x4 a0 = __builtin_amdgcn_mfma_f32_16x16x32_bf16(kb0, qa00, c, 0, 0, 0);
      st0[f] = __builtin_amdgcn_mfma_f32_16x16x32_bf16(kb1, qa01, a0, 0, 0, 0);
      f32x4 a1 = __builtin_amdgcn_mfma_f32_16x16x32_bf16(kb0, qa10, c, 0, 0, 0);
      st1[f] = __builtin_amdgcn_mfma_f32_16x16x32_bf16(kb1, qa11, a1, 0, 0, 0);
    }
    __builtin_amdgcn_s_setprio(0);

    union { uint32_t u[2]; bf16x4 v; } pa0[4], pa1[4];
#pragma unroll
    for (int f = 0; f < 2; ++f) {
      pa0[f].u[0] = cvt_pk(exp2f(st0[f][0]), exp2f(st0[f][1]));
      pa0[f].u[1] = cvt_pk(exp2f(st0[f][2]), exp2f(st0[f][3]));
      pa1[f].u[0] = cvt_pk(exp2f(st1[f][0]), exp2f(st1[f][1]));
      pa1[f].u[1] = cvt_pk(exp2f(st1[f][2]), exp2f(st1[f][3]));
    }

    __builtin_amdgcn_s_setprio(1);
#pragma unroll
    for (int f = 0; f < 2; ++f) {
      ol0 = mfma16(pa0[f].v, ones, ol0);
      ol1 = mfma16(pa1[f].v, ones, ol1);
#pragma unroll
      for (int nf = 0; nf < 4; ++nf) {
        const int vrow = (lo + 16 * nf) * 64;
        const int slot = (((2 * f + (hi >> 1)) ^ lo7) << 3) + ((hi & 1) << 2);
        const bf16x4 vb = *(const bf16x4*)&Vc[vrow + slot];
        o0[nf] = mfma16(pa0[f].v, vb, o0[nf]);
        o1[nf] = mfma16(pa1[f].v, vb, o1[nf]);
      }
    }
#pragma unroll
    for (int f = 2; f < 4; ++f) {
      pa0[f].u[0] = cvt_pk(exp2f(st0[f][0]), exp2f(st0[f][1]));
      pa0[f].u[1] = cvt_pk(exp2f(st0[f][2]), exp2f(st0[f][3]));
      pa1[f].u[0] = cvt_pk(exp2f(st1[f][0]), exp2f(st1[f][1]));
      pa1[f].u[1] = cvt_pk(exp2f(st1[f][2]), exp2f(st1[f][3]));
    }
#pragma unroll
    for (int f = 2; f < 4; ++f) {
      ol0 = mfma16(pa0[f].v, ones, ol0);
      ol1 = mfma16(pa1[f].v, ones, ol1);
#pragma unroll
      for (int nf = 0; nf < 4; ++nf) {
        const int vrow = (lo + 16 * nf) * 64;
        const int slot = (((2 * f + (hi >> 1)) ^ lo7) << 3) + ((hi & 1) << 2);
        const bf16x4 vb = *(const bf16x4*)&Vc[vrow + slot];
        o0[nf] = mfma16(pa0[f].v, vb, o0[nf]);
        o1[nf] = mfma16(pa1[f].v, vb, o1[nf]);
      }
    }
    __builtin_amdgcn_s_setprio(0);

    asm volatile("s_waitcnt lgkmcnt(0)" ::: "memory");
    __builtin_amdgcn_s_barrier();
  }
#undef STAGE

  float inv0[4], inv1[4];
#pragma unroll
  for (int i = 0; i < 4; ++i) { inv0[i] = 1.f / ol0[i]; inv1[i] = 1.f / ol1[i]; }
#pragma unroll
  for (int nf = 0; nf < 4; ++nf) {
#pragma unroll
    for (int i = 0; i < 4; ++i) {
      const int s0 = qt * 256 + w * 32 + hi * 4 + i;
      const int d = nf * 16 + lo;
      Ctx[((size_t)((b * 2048 + s0) * 16 + h)) * 64 + d] = f2bf(o0[nf][i] * inv0[i]);
      Ctx[((size_t)((b * 2048 + s0 + 16) * 16 + h)) * 64 + d] = f2bf(o1[nf][i] * inv1[i]);
    }
  }
}

extern "C" void kernel_launch(void* const* d_in, const int* in_sizes, int n_in,
                              void* d_out, int out_size, void* d_ws, size_t ws_size,
                              hipStream_t stream) {
  const float* q_in = (const float*)d_in[0];
  const float* k_in = (const float*)d_in[1];
  const float* v_in = (const float*)d_in[2];
  const float* mask = (const float*)d_in[3];
  const float* wq = (const float*)d_in[4];
  const float* bq = (const float*)d_in[5];
  const float* wk = (const float*)d_in[6];
  const float* bk = (const float*)d_in[7];
  const float* wv = (const float*)d_in[8];
  const float* bv = (const float*)d_in[9];
  const float* wo = (const float*)d_in[10];
  const float* bo = (const float*)d_in[11];

  // workspace: wT 8MB | Q 16MB | K 16MB | Vt 16MB | xbf/ctx 16MB | M2 32KB
  u16* ws  = (u16*)d_ws;
  u16* wtq = ws;
  u16* wtk = wtq + (1u << 20);
  u16* wtv = wtk + (1u << 20);
  u16* wto = wtv + (1u << 20);
  u16* Qb  = wto + (1u << 20);
  u16* Kb  = Qb + (size_t)8192 * 1024;
  u16* Vtb = Kb + (size_t)8192 * 1024;
  u16* xbf = Vtb + (size_t)8192 * 1024;  // doubles as ctx (dead by attn time)
  u16* ctx = xbf;
  float* M2 = (float*)(xbf + (size_t)8192 * 1024);

  transpose_w<<<dim3(16, 16, 4), 256, 0, stream>>>(wq, wk, wv, wo, wtq);
  prep_mask<<<32, 256, 0, stream>>>(mask, M2);

  convert_x<<<4096, 256, 0, stream>>>(q_in, xbf);
  gemm_proj<<<512, 512, 0, stream>>>(xbf, wtq, bq, Qb, nullptr, 0);
  convert_x<<<4096, 256, 0, stream>>>(k_in, xbf);
  gemm_proj<<<512, 512, 0, stream>>>(xbf, wtk, bk, Kb, nullptr, 1);
  convert_x<<<4096, 256, 0, stream>>>(v_in, xbf);
  gemm_proj<<<512, 512, 0, stream>>>(xbf, wtv, bv, Vtb, nullptr, 2);

  attn<<<512, 512, 0, stream>>>(Qb, Kb, Vtb, M2, ctx);

  gemm_proj<<<512, 512, 0, stream>>>(ctx, wto, bo, nullptr, (float*)d_out, 3);
}